// Round 2
// baseline (629.612 us; speedup 1.0000x reference)
//
#include <hip/hip_runtime.h>
#include <cstdint>
#include <cstddef>

// ---------------------------------------------------------------------------
// DynamicMemoryCell on MI355X (gfx950) — round 6 (resubmit; round-1 bench
// failed with GPUAcquisitionTimeout — never executed)
//
// Math: softmax over 1 key == 1 -> attn == v; q/k/pm dead.
// Linear chain pi->v->ctx->gi collapsed: Wcomb = Wih@Wop@Wv@Wip (per call).
//
// Round-6 vs round-5:
//   * Big GEMMs (fg, gi, gh, og) moved from the m97-style 128x128
//     single-buffered kernel (537 TF measured, MfmaUtil 22%) to a 256x256
//     BK=64 8-wave 4-phase-per-K-tile kernel:
//       - double-buffered LDS (128 KiB), global_load_lds width=16
//       - counted s_waitcnt vmcnt(4) twice per K-tile (never 0 in loop):
//         loads stay in flight across barriers (T3+T4)
//       - s_setprio(1) around each 16-MFMA cluster (T5; pays only with
//         phase-split schedules)
//       - LDS layout [kk-half][256 rows][32 cols] -> 64-B row stride ->
//         ds_read_b128 fragment reads are bank-conflict-free (lanes map
//         uniformly 8-per-16B-chunk), no swizzle needed
//   * Small weight-composition GEMMs stay on gemm64_k (grids too small
//     for 256^2 tiles).
// ---------------------------------------------------------------------------

typedef __bf16 bf16;
typedef bf16 bf16x4 __attribute__((ext_vector_type(4)));
typedef bf16 bf16x8 __attribute__((ext_vector_type(8)));
typedef float f32x4 __attribute__((ext_vector_type(4)));

#define B_ROWS 8192

__device__ __forceinline__ float sigmoid_f(float x) {
    return 1.0f / (1.0f + __expf(-x));
}
__device__ __forceinline__ float tanh_f(float x) {
    return 1.0f - 2.0f / (__expf(2.0f * x) + 1.0f);
}

// ---------------------------------------------------------------------------
// 256x256 BK=64 8-wave deep-pipelined GEMM: C[M,N] = A[M,K] @ W[N,K]^T + bias
// 512 threads = 8 waves (2M x 4N), wave tile 128x64, acc[8][4] f32x4.
// LDS per buffer: A[2][256][32] + B[2][256][32] bf16 = 64 KiB; dbuf = 128 KiB.
// Per K-tile: 4 phases (kk-half x n-half), each = {ds_read frags, stage one
// half-tile of tile kt+1 (2 x global_load_lds), barrier, lgkmcnt(0),
// setprio(1), 16 MFMA, setprio(0), [vmcnt(4) at phases 1,3], barrier}.
// FIFO invariant at each vmcnt(4): 8 loads outstanding, oldest 4 are the
// halves consumed by the next two phases. Last tile re-stages itself
// (redundant, keeps counts uniform); vmcnt(0) after the loop drains.
// epi 0: out_bf = bf16(val)
// epi 1: out_bf = bf16(aux_f32 * sigmoid(val))        (forget gate)
// epi 2: out_f32 = float(aux_bf) * sigmoid(val)       (output gate)
// ---------------------------------------------------------------------------
__global__ __launch_bounds__(512, 2) void gemm256_k(
    const bf16* __restrict__ A, int lda,
    const bf16* __restrict__ W, int ldw,
    const float* __restrict__ bias, int N, int K, int epi,
    bf16* __restrict__ out_bf, float* __restrict__ out_f32,
    const float* __restrict__ aux_f32, const bf16* __restrict__ aux_bf,
    int nby)
{
    __shared__ bf16 lds[65536];  // 128 KiB: [buf][A|B][kk][256][32]

    const int tid  = threadIdx.x;
    const int lane = tid & 63;
    const int wave = tid >> 6;
    const int wm   = wave >> 2;        // 0..1  (M half)
    const int wn   = wave & 3;         // 0..3  (N quarter)
    const int lrow = lane & 15;
    const int lq   = lane >> 4;

    const int by   = blockIdx.x % nby; // y-fastest: co-resident blocks share W
    const int bx   = blockIdx.x / nby;
    const int brow = by * 256;
    const int bcol = bx * 256;

    // staging decomposition: per inst 512 thr x 16 B = 128 rows x 64 B
    const int srow = tid >> 2;         // 0..127
    const int sc8  = (tid & 3) << 3;   // 0,8,16,24 (elem offset)

    f32x4 acc[8][4];
#pragma unroll
    for (int m = 0; m < 8; ++m)
#pragma unroll
        for (int n = 0; n < 4; ++n) {
            f32x4 z = {0.0f, 0.0f, 0.0f, 0.0f};
            acc[m][n] = z;
        }

    const int NT = K >> 6;

    // stage one 256x32 half (16 KiB) = 2 x global_load_lds(16B).
    // LDS write is linear in lane order (rule #21): elem (row*32+c) holds
    // G[g0+row, gk+c] — exactly what the fragment reads expect.
#define STAGE_HALF(G, ldg, g0, gk, dst)                                        \
    do {                                                                       \
        const bf16* gp0 = (G) + (size_t)((g0) + srow) * (ldg) + (gk) + sc8;    \
        const bf16* gp1 = gp0 + (size_t)128 * (ldg);                           \
        __builtin_amdgcn_global_load_lds(                                      \
            (const __attribute__((address_space(1))) void*)gp0,                \
            (__attribute__((address_space(3))) void*)((dst) + tid * 8),        \
            16, 0, 0);                                                         \
        __builtin_amdgcn_global_load_lds(                                      \
            (const __attribute__((address_space(1))) void*)gp1,                \
            (__attribute__((address_space(3))) void*)((dst) + 4096 + tid * 8), \
            16, 0, 0);                                                         \
    } while (0)

#define MFMA(d, a, b) \
    d = __builtin_amdgcn_mfma_f32_16x16x32_bf16(a, b, d, 0, 0, 0)

    // ---- prologue: tile 0 (all 4 halves) into buf0; wait first two halves
    {
        bf16* b0 = lds;
        STAGE_HALF(A, lda, brow, 0,  b0);               // A-k0
        STAGE_HALF(W, ldw, bcol, 0,  b0 + 16384);       // B-k0
        STAGE_HALF(A, lda, brow, 32, b0 + 8192);        // A-k1
        STAGE_HALF(W, ldw, bcol, 32, b0 + 16384 + 8192);// B-k1
    }
    asm volatile("s_waitcnt vmcnt(4)" ::: "memory");    // A-k0,B-k0 landed
    __builtin_amdgcn_s_barrier();
    asm volatile("" ::: "memory");

    for (int kt = 0; kt < NT; ++kt) {
        bf16* bufA = lds + (kt & 1) * 32768;
        bf16* bufB = bufA + 16384;
        bf16* nA   = lds + ((kt & 1) ^ 1) * 32768;
        bf16* nB   = nA + 16384;
        // next-tile k base; last tile re-stages itself (redundant but keeps
        // the per-wave vmcnt FIFO accounting uniform)
        const int kn = ((kt + 1 < NT) ? kt + 1 : kt) << 6;

        bf16x8 av[8];

        // ===== phase 0: kk=0, n-half 0 =====
        {
#pragma unroll
            for (int m = 0; m < 8; ++m)
                av[m] = *(const bf16x8*)(bufA + (wm * 128 + m * 16 + lrow) * 32 + lq * 8);
            bf16x8 b0 = *(const bf16x8*)(bufB + (wn * 64 +  0 + lrow) * 32 + lq * 8);
            bf16x8 b1 = *(const bf16x8*)(bufB + (wn * 64 + 16 + lrow) * 32 + lq * 8);
            STAGE_HALF(A, lda, brow, kn, nA);           // A-k0 of next
            __builtin_amdgcn_s_barrier();
            asm volatile("s_waitcnt lgkmcnt(0)" ::: "memory");
            __builtin_amdgcn_s_setprio(1);
#pragma unroll
            for (int m = 0; m < 8; ++m) {
                MFMA(acc[m][0], av[m], b0);
                MFMA(acc[m][1], av[m], b1);
            }
            __builtin_amdgcn_s_setprio(0);
            __builtin_amdgcn_s_barrier();
            asm volatile("" ::: "memory");
        }

        // ===== phase 1: kk=0, n-half 1 =====
        {
            bf16x8 b2 = *(const bf16x8*)(bufB + (wn * 64 + 32 + lrow) * 32 + lq * 8);
            bf16x8 b3 = *(const bf16x8*)(bufB + (wn * 64 + 48 + lrow) * 32 + lq * 8);
            STAGE_HALF(W, ldw, bcol, kn, nB);           // B-k0 of next
            __builtin_amdgcn_s_barrier();
            asm volatile("s_waitcnt lgkmcnt(0)" ::: "memory");
            __builtin_amdgcn_s_setprio(1);
#pragma unroll
            for (int m = 0; m < 8; ++m) {
                MFMA(acc[m][2], av[m], b2);
                MFMA(acc[m][3], av[m], b3);
            }
            __builtin_amdgcn_s_setprio(0);
            // drain current tile's A-k1,B-k1 (issued 2 phases-pairs ago);
            // next tile's A-k0,B-k0 (4 loads) stay in flight
            asm volatile("s_waitcnt vmcnt(4)" ::: "memory");
            __builtin_amdgcn_s_barrier();
            asm volatile("" ::: "memory");
        }

        // ===== phase 2: kk=1, n-half 0 =====
        {
#pragma unroll
            for (int m = 0; m < 8; ++m)
                av[m] = *(const bf16x8*)(bufA + 8192 + (wm * 128 + m * 16 + lrow) * 32 + lq * 8);
            bf16x8 b0 = *(const bf16x8*)(bufB + 8192 + (wn * 64 +  0 + lrow) * 32 + lq * 8);
            bf16x8 b1 = *(const bf16x8*)(bufB + 8192 + (wn * 64 + 16 + lrow) * 32 + lq * 8);
            STAGE_HALF(A, lda, brow, kn + 32, nA + 8192); // A-k1 of next
            __builtin_amdgcn_s_barrier();
            asm volatile("s_waitcnt lgkmcnt(0)" ::: "memory");
            __builtin_amdgcn_s_setprio(1);
#pragma unroll
            for (int m = 0; m < 8; ++m) {
                MFMA(acc[m][0], av[m], b0);
                MFMA(acc[m][1], av[m], b1);
            }
            __builtin_amdgcn_s_setprio(0);
            __builtin_amdgcn_s_barrier();
            asm volatile("" ::: "memory");
        }

        // ===== phase 3: kk=1, n-half 1 =====
        {
            bf16x8 b2 = *(const bf16x8*)(bufB + 8192 + (wn * 64 + 32 + lrow) * 32 + lq * 8);
            bf16x8 b3 = *(const bf16x8*)(bufB + 8192 + (wn * 64 + 48 + lrow) * 32 + lq * 8);
            STAGE_HALF(W, ldw, bcol, kn + 32, nB + 8192); // B-k1 of next
            __builtin_amdgcn_s_barrier();
            asm volatile("s_waitcnt lgkmcnt(0)" ::: "memory");
            __builtin_amdgcn_s_setprio(1);
#pragma unroll
            for (int m = 0; m < 8; ++m) {
                MFMA(acc[m][2], av[m], b2);
                MFMA(acc[m][3], av[m], b3);
            }
            __builtin_amdgcn_s_setprio(0);
            // drain next tile's A-k0,B-k0; its A-k1,B-k1 stay in flight
            asm volatile("s_waitcnt vmcnt(4)" ::: "memory");
            __builtin_amdgcn_s_barrier();
            asm volatile("" ::: "memory");
        }
    }

    // drain redundant last-tile stages before block exit (LDS reallocation)
    asm volatile("s_waitcnt vmcnt(0)" ::: "memory");

    // epilogue: C/D layout col = lane&15, row = (lane>>4)*4 + reg
#pragma unroll
    for (int n = 0; n < 4; ++n) {
        const int gcol = bcol + wn * 64 + n * 16 + lrow;
        const float bj = bias ? bias[gcol] : 0.0f;
#pragma unroll
        for (int m = 0; m < 8; ++m) {
            const int growb = brow + wm * 128 + m * 16 + lq * 4;
#pragma unroll
            for (int r = 0; r < 4; ++r) {
                const int grow = growb + r;
                const float val = acc[m][n][r] + bj;
                if (epi == 0) {
                    out_bf[(size_t)grow * N + gcol] = (bf16)val;
                } else if (epi == 1) {
                    const size_t idx = (size_t)grow * N + gcol;
                    out_bf[idx] = (bf16)(aux_f32[idx] * sigmoid_f(val));
                } else {
                    const size_t idx = (size_t)grow * N + gcol;
                    out_f32[idx] = (float)aux_bf[idx] * sigmoid_f(val);
                }
            }
        }
    }
#undef STAGE_HALF
#undef MFMA
}

// ---------------------------------------------------------------------------
// m97-style GEMM core kept for the small 1024^3 weight-composition GEMMs.
// epi 0: out_bf = bf16(val);  epi 3: out_bf[gcol*tld + grow] (transposed)
// ---------------------------------------------------------------------------
template <int BM>
__device__ __forceinline__ void gemm_core(
    bf16* sA, bf16* sB,
    const bf16* __restrict__ A, int lda,
    const bf16* __restrict__ W, int ldw,
    const float* __restrict__ bias,
    int N, int K, int brow, int bcol, int epi,
    bf16* __restrict__ out_bf, float* __restrict__ out_f32,
    const float* __restrict__ aux_f32, const bf16* __restrict__ aux_bf,
    int tld)
{
    constexpr int AI = BM / 32;
    const int tid  = threadIdx.x;
    const int lane = tid & 63;
    const int wave = tid >> 6;
    const int wr   = (wave & 1) * (BM / 2);
    const int wc   = (wave >> 1) * 64;
    const int lrow = lane & 15;
    const int lq   = lane >> 4;

    f32x4 acc[AI][4];
#pragma unroll
    for (int i = 0; i < AI; ++i)
#pragma unroll
        for (int j = 0; j < 4; ++j) {
            f32x4 z = {0.0f, 0.0f, 0.0f, 0.0f};
            acc[i][j] = z;
        }

    for (int k0 = 0; k0 < K; k0 += 32) {
#pragma unroll
        for (int i = 0; i < BM / 64; ++i) {
            int s = tid + i * 256;
            int row = s >> 2, col = (s & 3) << 3;
            const bf16* gp = A + (size_t)(brow + row) * lda + (k0 + col);
            __builtin_amdgcn_global_load_lds(
                (const __attribute__((address_space(1))) void*)gp,
                (__attribute__((address_space(3))) void*)(&sA[s * 8]),
                16, 0, 0);
        }
#pragma unroll
        for (int i = 0; i < 2; ++i) {
            int s = tid + i * 256;
            int row = s >> 2, col = (s & 3) << 3;
            const bf16* gp = W + (size_t)(bcol + row) * ldw + (k0 + col);
            __builtin_amdgcn_global_load_lds(
                (const __attribute__((address_space(1))) void*)gp,
                (__attribute__((address_space(3))) void*)(&sB[s * 8]),
                16, 0, 0);
        }
        __syncthreads();

        bf16x8 av[AI], bvf[4];
#pragma unroll
        for (int i = 0; i < AI; ++i)
            av[i] = *(const bf16x8*)&sA[(wr + i * 16 + lrow) * 32 + lq * 8];
#pragma unroll
        for (int j = 0; j < 4; ++j)
            bvf[j] = *(const bf16x8*)&sB[(wc + j * 16 + lrow) * 32 + lq * 8];

#pragma unroll
        for (int i = 0; i < AI; ++i)
#pragma unroll
            for (int j = 0; j < 4; ++j)
                acc[i][j] = __builtin_amdgcn_mfma_f32_16x16x32_bf16(
                    av[i], bvf[j], acc[i][j], 0, 0, 0);

        __syncthreads();
    }

#pragma unroll
    for (int j = 0; j < 4; ++j) {
        const int gcol = bcol + wc + j * 16 + lrow;
        const float bj = bias ? bias[gcol] : 0.0f;
#pragma unroll
        for (int i = 0; i < AI; ++i) {
            const int growb = brow + wr + i * 16 + lq * 4;
#pragma unroll
            for (int r = 0; r < 4; ++r) {
                const int grow = growb + r;
                const float val = acc[i][j][r] + bj;
                if (epi == 0) {
                    out_bf[(size_t)grow * N + gcol] = (bf16)val;
                } else if (epi == 1) {
                    const size_t idx = (size_t)grow * N + gcol;
                    out_bf[idx] = (bf16)(aux_f32[idx] * sigmoid_f(val));
                } else if (epi == 2) {
                    const size_t idx = (size_t)grow * N + gcol;
                    out_f32[idx] = (float)aux_bf[idx] * sigmoid_f(val);
                } else {
                    out_bf[(size_t)gcol * tld + grow] = (bf16)val;
                }
            }
        }
    }
}

__global__ __launch_bounds__(256, 2) void gemm128_k(
    const bf16* __restrict__ A, int lda, const bf16* __restrict__ W, int ldw,
    const float* __restrict__ bias, int N, int K, int epi,
    bf16* __restrict__ out_bf, float* __restrict__ out_f32,
    const float* __restrict__ aux_f32, const bf16* __restrict__ aux_bf,
    int tld, int nby)
{
    __shared__ bf16 sA[128 * 32];
    __shared__ bf16 sB[128 * 32];
    const int by = blockIdx.x % nby;
    const int bx = blockIdx.x / nby;
    gemm_core<128>(sA, sB, A, lda, W, ldw, bias, N, K,
                   by * 128, bx * 128, epi,
                   out_bf, out_f32, aux_f32, aux_bf, tld);
}

__global__ __launch_bounds__(256, 2) void gemm64_k(
    const bf16* __restrict__ A, int lda, const bf16* __restrict__ W, int ldw,
    const float* __restrict__ bias, int N, int K, int epi,
    bf16* __restrict__ out_bf, float* __restrict__ out_f32,
    const float* __restrict__ aux_f32, const bf16* __restrict__ aux_bf,
    int tld, int nby)
{
    __shared__ bf16 sA[64 * 32];
    __shared__ bf16 sB[128 * 32];
    const int by = blockIdx.x % nby;
    const int bx = blockIdx.x / nby;
    gemm_core<64>(sA, sB, A, lda, W, ldw, bias, N, K,
                  by * 64, bx * 128, epi,
                  out_bf, out_f32, aux_f32, aux_bf, tld);
}

// ---------------------------------------------------------------------------
// Elementwise / small helpers
// ---------------------------------------------------------------------------

__global__ void cast_weights_k(
    const float* __restrict__ wv, const float* __restrict__ wop,
    const float* __restrict__ wih, const float* __restrict__ wfg,
    const float* __restrict__ wog,
    bf16* __restrict__ dv, bf16* __restrict__ dop, bf16* __restrict__ dih,
    bf16* __restrict__ dfg, bf16* __restrict__ dog)
{
    int c = blockIdx.x * 256 + threadIdx.x;  // [0, 2097152)
    const float* s;
    bf16* d;
    int o;
    if (c < 262144)        { s = wv;  d = dv;  o = c; }
    else if (c < 524288)   { s = wop; d = dop; o = c - 262144; }
    else if (c < 1310720)  { s = wih; d = dih; o = c - 524288; }
    else if (c < 1835008)  { s = wfg; d = dfg; o = c - 1310720; }
    else                   { s = wog; d = dog; o = c - 1835008; }
    f32x4 v = ((const f32x4*)s)[o];
    bf16x4 t = {(bf16)v[0], (bf16)v[1], (bf16)v[2], (bf16)v[3]};
    ((bf16x4*)d)[o] = t;
}

__global__ void cast_f32_bf16_k(const float* __restrict__ src,
                                bf16* __restrict__ dst, int n4) {
    int i = blockIdx.x * 256 + threadIdx.x;
    if (i >= n4) return;
    f32x4 v = ((const f32x4*)src)[i];
    bf16x4 o = {(bf16)v[0], (bf16)v[1], (bf16)v[2], (bf16)v[3]};
    ((bf16x4*)dst)[i] = o;
}

__global__ void build_cat_k(const float* __restrict__ mem,
                            const float* __restrict__ inp,
                            bf16* __restrict__ cat) {
    int i = blockIdx.x * 256 + threadIdx.x;
    int row = i >> 9;
    int c4  = i & 511;
    f32x4 v;
    if (c4 < 256)
        v = ((const f32x4*)mem)[(size_t)row * 256 + c4];
    else
        v = ((const f32x4*)inp)[(size_t)row * 256 + (c4 - 256)];
    bf16x4 o = {(bf16)v[0], (bf16)v[1], (bf16)v[2], (bf16)v[3]};
    ((bf16x4*)cat)[i] = o;
}

// src [R,C] f32  ->  dst [C,R] bf16
__global__ void transpose_cast_k(const float* __restrict__ src,
                                 bf16* __restrict__ dst, int R, int C) {
    __shared__ float t[32][33];
    int bx = blockIdx.x * 32;
    int by = blockIdx.y * 32;
    int tx = threadIdx.x & 31, ty = threadIdx.x >> 5;
#pragma unroll
    for (int i = 0; i < 32; i += 8)
        t[ty + i][tx] = src[(size_t)(by + ty + i) * C + bx + tx];
    __syncthreads();
#pragma unroll
    for (int i = 0; i < 32; i += 8)
        dst[(size_t)(bx + ty + i) * R + by + tx] = (bf16)t[tx][ty + i];
}

// y[n] = b[n] + sum_k W[n,k] * x[k]   (fp32; one wave per output row)
__global__ void gemv_k(const float* __restrict__ W, const float* __restrict__ x,
                       const float* __restrict__ b, float* __restrict__ y,
                       int K) {
    int n    = blockIdx.x * 4 + (threadIdx.x >> 6);
    int lane = threadIdx.x & 63;
    const float* row = W + (size_t)n * K;
    float s = 0.0f;
    for (int k = lane * 4; k < K; k += 256) {
        f32x4 w = *(const f32x4*)(row + k);
        f32x4 xv = *(const f32x4*)(x + k);
        s += w[0] * xv[0] + w[1] * xv[1] + w[2] * xv[2] + w[3] * xv[3];
    }
#pragma unroll
    for (int off = 32; off; off >>= 1) s += __shfl_down(s, off);
    if (lane == 0) y[n] = s + b[n];
}

// GRU combine, in place: upd (=gated buffer) = (1-z)*n + z*gated
__global__ void gru_combine_k(const bf16* __restrict__ gi,
                              const bf16* __restrict__ gh,
                              bf16* __restrict__ gated) {
    int i   = blockIdx.x * 256 + threadIdx.x;
    int row = i >> 7;
    int c   = (i & 127) << 3;
    size_t b3 = (size_t)row * 3072 + c;
    size_t b1 = (size_t)row * 1024 + c;
    bf16x8 gir = *(const bf16x8*)(gi + b3);
    bf16x8 giz = *(const bf16x8*)(gi + b3 + 1024);
    bf16x8 gin = *(const bf16x8*)(gi + b3 + 2048);
    bf16x8 ghr = *(const bf16x8*)(gh + b3);
    bf16x8 ghz = *(const bf16x8*)(gh + b3 + 1024);
    bf16x8 ghn = *(const bf16x8*)(gh + b3 + 2048);
    bf16x8 g   = *(const bf16x8*)(gated + b1);
    bf16x8 o;
#pragma unroll
    for (int e = 0; e < 8; ++e) {
        float r = sigmoid_f((float)gir[e] + (float)ghr[e]);
        float z = sigmoid_f((float)giz[e] + (float)ghz[e]);
        float n = tanh_f((float)gin[e] + r * (float)ghn[e]);
        o[e] = (bf16)((1.0f - z) * n + z * (float)g[e]);
    }
    *(bf16x8*)(gated + b1) = o;
}

__global__ void fill_ones_k(float* __restrict__ p, int n) {
    int i = blockIdx.x * 256 + threadIdx.x;
    if (i < n) p[i] = 1.0f;
}

// ---------------------------------------------------------------------------
// Launch
// ---------------------------------------------------------------------------
extern "C" void kernel_launch(void* const* d_in, const int* in_sizes, int n_in,
                              void* d_out, int out_size, void* d_ws,
                              size_t ws_size, hipStream_t stream) {
    const float* input      = (const float*)d_in[0];
    const float* prev       = (const float*)d_in[1];
    const float* in_proj_w  = (const float*)d_in[2];
    const float* in_proj_b  = (const float*)d_in[3];
    const float* out_proj_w = (const float*)d_in[4];
    const float* out_proj_b = (const float*)d_in[5];
    const float* ip_w       = (const float*)d_in[6];
    const float* ip_b       = (const float*)d_in[7];
    // d_in[8]/d_in[9] (mp_w/mp_b) dead: softmax over one key == 1
    const float* fg_w  = (const float*)d_in[10];
    const float* fg_b  = (const float*)d_in[11];
    const float* og_w  = (const float*)d_in[12];
    const float* og_b  = (const float*)d_in[13];
    const float* gih_w = (const float*)d_in[14];
    const float* gih_b = (const float*)d_in[15];
    const float* ghh_w = (const float*)d_in[16];
    const float* ghh_b = (const float*)d_in[17];
    float* out = (float*)d_out;

    // ---- workspace layout (152 MiB, overlaps respect dependency order)
    char* ws = (char*)d_ws;
    const size_t MB = 1024 * 1024;
    bf16* CAT   = (bf16*)(ws);             // [0,32M)  live until gi done
    bf16* WHHB  = (bf16*)(ws);             // 6M, cast AFTER gi (overlaps CAT)
    bf16* GI    = (bf16*)(ws + 32 * MB);   // [32,80M)
    bf16* GH    = (bf16*)(ws + 80 * MB);   // [80,128M) written late
    // temporaries inside the GH region (dead before GH is written):
    bf16* WVB   = (bf16*)(ws + 80 * MB);   // 2M
    bf16* WOPB  = (bf16*)(ws + 82 * MB);   // 2M
    bf16* WIHB  = (bf16*)(ws + 84 * MB);   // 6M
    bf16* WIPT  = (bf16*)(ws + 90 * MB);   // 2M
    bf16* T1T   = (bf16*)(ws + 92 * MB);   // 2M
    bf16* T2T   = (bf16*)(ws + 94 * MB);   // 2M
    bf16* WFGB  = (bf16*)(ws + 96 * MB);   // 4M
    float* T1B  = (float*)(ws + 100 * MB);
    float* T2B  = (float*)(ws + 100 * MB + 8192);
    float* T3B  = (float*)(ws + 100 * MB + 16384);
    bf16* GATED = (bf16*)(ws + 128 * MB);  // [128,144M); becomes UPD in place
    bf16* WCOMB = (bf16*)(ws + 144 * MB);  // [144,150M)
    bf16* WOGB  = (bf16*)(ws + 150 * MB);  // [150,152M)

    const int M = B_ROWS;
    dim3 blk(256);
    dim3 blk512(512);

    // 1. activations -> bf16 concat
    build_cat_k<<<dim3((M * 2048 / 4) / 256), blk, 0, stream>>>(prev, input, CAT);
    // 2. all front weight casts in one launch
    cast_weights_k<<<dim3(8192), blk, 0, stream>>>(
        in_proj_w + 2048 * 1024, out_proj_w, gih_w, fg_w, og_w,
        WVB, WOPB, WIHB, WFGB, WOGB);
    // 3. Wip^T (bf16)
    transpose_cast_k<<<dim3(32, 32), blk, 0, stream>>>(ip_w, WIPT, 1024, 1024);
    // 4. bias chain (fp32, exact)
    gemv_k<<<dim3(256), blk, 0, stream>>>(in_proj_w + 2048 * 1024, ip_b, in_proj_b + 2048, T1B, 1024);
    gemv_k<<<dim3(256), blk, 0, stream>>>(out_proj_w, T1B, out_proj_b, T2B, 1024);
    gemv_k<<<dim3(768), blk, 0, stream>>>(gih_w, T2B, gih_b, T3B, 1024);
    // 5-7. weight composition: Wcomb = Wih @ Wop @ Wv @ Wip
    gemm64_k<<<dim3(128), blk, 0, stream>>>(WVB, 1024, WIPT, 1024, nullptr,
        1024, 1024, 3, T1T, nullptr, nullptr, nullptr, 1024, 16);  // (Wv@Wip)^T
    gemm64_k<<<dim3(128), blk, 0, stream>>>(WOPB, 1024, T1T, 1024, nullptr,
        1024, 1024, 3, T2T, nullptr, nullptr, nullptr, 1024, 16);  // (Wop@..)^T
    gemm64_k<<<dim3(384), blk, 0, stream>>>(WIHB, 1024, T2T, 1024, nullptr,
        1024, 1024, 0, WCOMB, nullptr, nullptr, nullptr, 0, 48);   // Wcomb
    // 8. gated = prev * sigmoid(cat @ Wfg^T + bfg)   [256^2 4-phase]
    gemm256_k<<<dim3(128), blk512, 0, stream>>>(CAT, 2048, WFGB, 2048,
        fg_b, 1024, 2048, 1, GATED, nullptr, prev, nullptr, 32);
    // 9. gi = x @ Wcomb^T + bcomb                    [256^2 4-phase]
    gemm256_k<<<dim3(384), blk512, 0, stream>>>(CAT + 1024, 2048, WCOMB,
        1024, T3B, 3072, 1024, 0, GI, nullptr, nullptr, nullptr, 32);
    // 10. Whh cast (CAT now dead)
    cast_f32_bf16_k<<<dim3(3072), blk, 0, stream>>>(ghh_w, WHHB, 3072 * 1024 / 4);
    // 11. gh = gated @ Whh^T + bhh                   [256^2 4-phase]
    gemm256_k<<<dim3(384), blk512, 0, stream>>>(GATED, 1024, WHHB, 1024,
        ghh_b, 3072, 1024, 0, GH, nullptr, nullptr, nullptr, 32);
    // 12. GRU combine (in place: GATED becomes UPD)
    gru_combine_k<<<dim3(M * 1024 / 8 / 256), blk, 0, stream>>>(GI, GH, GATED);
    // 13. out = upd * sigmoid(upd @ Wog^T + bog)     [256^2 4-phase]
    gemm256_k<<<dim3(128), blk512, 0, stream>>>(GATED, 1024, WOGB, 1024,
        og_b, 1024, 1024, 2, nullptr, out, nullptr, GATED, 32);
    // 14. attention weights == 1.0
    fill_ones_k<<<dim3(32), blk, 0, stream>>>(out + (size_t)M * 1024, M);
}

// Round 3
// 524.633 us; speedup vs baseline: 1.2001x; 1.2001x over previous
//
#include <hip/hip_runtime.h>
#include <cstdint>
#include <cstddef>

// ---------------------------------------------------------------------------
// DynamicMemoryCell on MI355X (gfx950) — round 7
//
// Math: softmax over 1 key == 1 -> attn == v; q/k/pm dead.
// Linear chain pi->v->ctx->gi collapsed: Wcomb = Wih@Wop@Wv@Wip (per call).
//
// Round-7 vs round-6 (256^2 4-phase REGRESSED 546->630: 1 block/CU occupancy
// collapse + half-idle grids at N=1024; reverted) and vs round-5:
//   * keep 128^2 tile / 4 waves / round-5 grids (good fill: 512-1536 blocks)
//   * 2-phase DOUBLE-buffered BK=32 pipeline: ds_read(cur) -> stage(next)
//     -> MFMA -> vmcnt(0) -> raw s_barrier. Load latency hides under MFMA
//     instead of being serially exposed by __syncthreads' vmcnt(0) drain
//     BEFORE compute (round-5 structure).
//   * LDS 32 KiB/block -> 5 blocks/CU (~20 waves/CU vs ~10): more TLP.
//   * 2-way-minimal XOR swizzle on LDS chunks, applied on BOTH the staged
//     global source col and the ds_read col (rule #21). Old layout was an
//     8-way conflict (bank = 16*(r&1)+4*lq; rows 2 apart alias) -> the
//     measured 6.29M SQ_LDS_BANK_CONFLICT. New: (parity,chunk) pairs each
//     hit 2x per 16-lane group -> 2-way = free (m136).
// ---------------------------------------------------------------------------

typedef __bf16 bf16;
typedef bf16 bf16x4 __attribute__((ext_vector_type(4)));
typedef bf16 bf16x8 __attribute__((ext_vector_type(8)));
typedef float f32x4 __attribute__((ext_vector_type(4)));

#define B_ROWS 8192

__device__ __forceinline__ float sigmoid_f(float x) {
    return 1.0f / (1.0f + __expf(-x));
}
__device__ __forceinline__ float tanh_f(float x) {
    return 1.0f - 2.0f / (__expf(2.0f * x) + 1.0f);
}

// ---------------------------------------------------------------------------
// Double-buffered GEMM core: C[M,N] = A[M,K] @ W[N,K]^T + bias.
// Block tile BM x 128, BK=32, 4 waves; wave tile (BM/2) x 64 via
// mfma_f32_16x16x32_bf16. sA: 2 x BM x 32, sB: 2 x 128 x 32 (bf16).
// Per K-step: ds_read frags (swizzled) -> stage next tile (global_load_lds
// w=16, linear LDS dest, inverse-swizzled global src) -> 16 MFMA ->
// sched_barrier -> s_waitcnt vmcnt(0) lgkmcnt(0) -> s_barrier.
// epi 0: out_bf = bf16(val)
// epi 1: out_bf = bf16(aux_f32 * sigmoid(val))        (forget gate)
// epi 2: out_f32 = float(aux_bf) * sigmoid(val)       (output gate)
// epi 3: out_bf[gcol*tld + grow] = bf16(val)          (transposed store)
// ---------------------------------------------------------------------------
template <int BM>
__device__ __forceinline__ void gemm_core_db(
    bf16* sA, bf16* sB,
    const bf16* __restrict__ A, int lda,
    const bf16* __restrict__ W, int ldw,
    const float* __restrict__ bias,
    int N, int K, int brow, int bcol, int epi,
    bf16* __restrict__ out_bf, float* __restrict__ out_f32,
    const float* __restrict__ aux_f32, const bf16* __restrict__ aux_bf,
    int tld)
{
    constexpr int AI = BM / 32;
    const int tid  = threadIdx.x;
    const int lane = tid & 63;
    const int wave = tid >> 6;
    const int wr   = (wave & 1) * (BM / 2);
    const int wc   = (wave >> 1) * 64;
    const int lrow = lane & 15;
    const int lq   = lane >> 4;

    f32x4 acc[AI][4];
#pragma unroll
    for (int i = 0; i < AI; ++i)
#pragma unroll
        for (int j = 0; j < 4; ++j) {
            f32x4 z = {0.0f, 0.0f, 0.0f, 0.0f};
            acc[i][j] = z;
        }

    // stage tile (k0) into buffer sel. LDS dest linear (rule #21); swizzle
    // applied by permuting the GLOBAL source column within each row-pair.
    auto stage = [&](int sel, int k0) {
#pragma unroll
        for (int i = 0; i < BM / 64; ++i) {
            const int s   = tid + i * 256;
            const int row = s >> 2;
            const int col = (((s & 3) ^ ((s >> 3) & 3)) << 3);
            const bf16* gp = A + (size_t)(brow + row) * lda + (k0 + col);
            __builtin_amdgcn_global_load_lds(
                (const __attribute__((address_space(1))) void*)gp,
                (__attribute__((address_space(3))) void*)(&sA[sel * (BM * 32) + s * 8]),
                16, 0, 0);
        }
#pragma unroll
        for (int i = 0; i < 2; ++i) {
            const int s   = tid + i * 256;
            const int row = s >> 2;
            const int col = (((s & 3) ^ ((s >> 3) & 3)) << 3);
            const bf16* gp = W + (size_t)(bcol + row) * ldw + (k0 + col);
            __builtin_amdgcn_global_load_lds(
                (const __attribute__((address_space(1))) void*)gp,
                (__attribute__((address_space(3))) void*)(&sB[sel * 4096 + s * 8]),
                16, 0, 0);
        }
    };

    const int NT = K >> 5;

    // prologue: tile 0 into buf 0
    stage(0, 0);
    asm volatile("s_waitcnt vmcnt(0)" ::: "memory");
    __builtin_amdgcn_s_barrier();
    __builtin_amdgcn_sched_barrier(0);

    for (int kt = 0; kt < NT; ++kt) {
        const int cur = kt & 1;
        bf16* cA = sA + cur * (BM * 32);
        bf16* cB = sB + cur * 4096;

        // fragment reads (swizzled chunk: lq ^ ((r>>1)&3))
        bf16x8 av[AI], bv[4];
#pragma unroll
        for (int i = 0; i < AI; ++i) {
            const int r = wr + i * 16 + lrow;
            av[i] = *(const bf16x8*)&cA[r * 32 + ((lq ^ ((r >> 1) & 3)) << 3)];
        }
#pragma unroll
        for (int j = 0; j < 4; ++j) {
            const int r = wc + j * 16 + lrow;
            bv[j] = *(const bf16x8*)&cB[r * 32 + ((lq ^ ((r >> 1) & 3)) << 3)];
        }

        // issue next-tile stage; its latency hides under the MFMAs below
        if (kt + 1 < NT) stage(cur ^ 1, (kt + 1) << 5);

        // compiler inserts lgkm waits for av/bv before first use
#pragma unroll
        for (int i = 0; i < AI; ++i)
#pragma unroll
            for (int j = 0; j < 4; ++j)
                acc[i][j] = __builtin_amdgcn_mfma_f32_16x16x32_bf16(
                    av[i], bv[j], acc[i][j], 0, 0, 0);

        __builtin_amdgcn_sched_barrier(0);
        asm volatile("s_waitcnt vmcnt(0) lgkmcnt(0)" ::: "memory");
        __builtin_amdgcn_s_barrier();
        __builtin_amdgcn_sched_barrier(0);
    }

    // epilogue: C/D layout col = lane&15, row = (lane>>4)*4 + reg
#pragma unroll
    for (int j = 0; j < 4; ++j) {
        const int gcol = bcol + wc + j * 16 + lrow;
        const float bj = bias ? bias[gcol] : 0.0f;
#pragma unroll
        for (int i = 0; i < AI; ++i) {
            const int growb = brow + wr + i * 16 + lq * 4;
#pragma unroll
            for (int r = 0; r < 4; ++r) {
                const int grow = growb + r;
                const float val = acc[i][j][r] + bj;
                if (epi == 0) {
                    out_bf[(size_t)grow * N + gcol] = (bf16)val;
                } else if (epi == 1) {
                    const size_t idx = (size_t)grow * N + gcol;
                    out_bf[idx] = (bf16)(aux_f32[idx] * sigmoid_f(val));
                } else if (epi == 2) {
                    const size_t idx = (size_t)grow * N + gcol;
                    out_f32[idx] = (float)aux_bf[idx] * sigmoid_f(val);
                } else {
                    out_bf[(size_t)gcol * tld + grow] = (bf16)val;
                }
            }
        }
    }
}

// 1-D grid, y-fastest decode: by = id % nby, bx = id / nby. Co-resident
// blocks then share A row-tiles (same bx phase) -> L3 absorbs the re-reads.
__global__ __launch_bounds__(256, 2) void gemm128_k(
    const bf16* __restrict__ A, int lda, const bf16* __restrict__ W, int ldw,
    const float* __restrict__ bias, int N, int K, int epi,
    bf16* __restrict__ out_bf, float* __restrict__ out_f32,
    const float* __restrict__ aux_f32, const bf16* __restrict__ aux_bf,
    int tld, int nby)
{
    __shared__ bf16 sA[2 * 128 * 32];
    __shared__ bf16 sB[2 * 128 * 32];
    const int by = blockIdx.x % nby;
    const int bx = blockIdx.x / nby;
    gemm_core_db<128>(sA, sB, A, lda, W, ldw, bias, N, K,
                      by * 128, bx * 128, epi,
                      out_bf, out_f32, aux_f32, aux_bf, tld);
}

__global__ __launch_bounds__(256, 2) void gemm64_k(
    const bf16* __restrict__ A, int lda, const bf16* __restrict__ W, int ldw,
    const float* __restrict__ bias, int N, int K, int epi,
    bf16* __restrict__ out_bf, float* __restrict__ out_f32,
    const float* __restrict__ aux_f32, const bf16* __restrict__ aux_bf,
    int tld, int nby)
{
    __shared__ bf16 sA[2 * 64 * 32];
    __shared__ bf16 sB[2 * 128 * 32];
    const int by = blockIdx.x % nby;
    const int bx = blockIdx.x / nby;
    gemm_core_db<64>(sA, sB, A, lda, W, ldw, bias, N, K,
                     by * 64, bx * 128, epi,
                     out_bf, out_f32, aux_f32, aux_bf, tld);
}

// ---------------------------------------------------------------------------
// Elementwise / small helpers
// ---------------------------------------------------------------------------

// One launch casting all 5 front weights. Chunk = 4 floats. Segment table
// hardcoded for this problem's sizes.
__global__ void cast_weights_k(
    const float* __restrict__ wv, const float* __restrict__ wop,
    const float* __restrict__ wih, const float* __restrict__ wfg,
    const float* __restrict__ wog,
    bf16* __restrict__ dv, bf16* __restrict__ dop, bf16* __restrict__ dih,
    bf16* __restrict__ dfg, bf16* __restrict__ dog)
{
    int c = blockIdx.x * 256 + threadIdx.x;  // [0, 2097152)
    const float* s;
    bf16* d;
    int o;
    if (c < 262144)        { s = wv;  d = dv;  o = c; }
    else if (c < 524288)   { s = wop; d = dop; o = c - 262144; }
    else if (c < 1310720)  { s = wih; d = dih; o = c - 524288; }
    else if (c < 1835008)  { s = wfg; d = dfg; o = c - 1310720; }
    else                   { s = wog; d = dog; o = c - 1835008; }
    f32x4 v = ((const f32x4*)s)[o];
    bf16x4 t = {(bf16)v[0], (bf16)v[1], (bf16)v[2], (bf16)v[3]};
    ((bf16x4*)d)[o] = t;
}

__global__ void cast_f32_bf16_k(const float* __restrict__ src,
                                bf16* __restrict__ dst, int n4) {
    int i = blockIdx.x * 256 + threadIdx.x;
    if (i >= n4) return;
    f32x4 v = ((const f32x4*)src)[i];
    bf16x4 o = {(bf16)v[0], (bf16)v[1], (bf16)v[2], (bf16)v[3]};
    ((bf16x4*)dst)[i] = o;
}

__global__ void build_cat_k(const float* __restrict__ mem,
                            const float* __restrict__ inp,
                            bf16* __restrict__ cat) {
    int i = blockIdx.x * 256 + threadIdx.x;
    int row = i >> 9;
    int c4  = i & 511;
    f32x4 v;
    if (c4 < 256)
        v = ((const f32x4*)mem)[(size_t)row * 256 + c4];
    else
        v = ((const f32x4*)inp)[(size_t)row * 256 + (c4 - 256)];
    bf16x4 o = {(bf16)v[0], (bf16)v[1], (bf16)v[2], (bf16)v[3]};
    ((bf16x4*)cat)[i] = o;
}

// src [R,C] f32  ->  dst [C,R] bf16
__global__ void transpose_cast_k(const float* __restrict__ src,
                                 bf16* __restrict__ dst, int R, int C) {
    __shared__ float t[32][33];
    int bx = blockIdx.x * 32;
    int by = blockIdx.y * 32;
    int tx = threadIdx.x & 31, ty = threadIdx.x >> 5;
#pragma unroll
    for (int i = 0; i < 32; i += 8)
        t[ty + i][tx] = src[(size_t)(by + ty + i) * C + bx + tx];
    __syncthreads();
#pragma unroll
    for (int i = 0; i < 32; i += 8)
        dst[(size_t)(bx + ty + i) * R + by + tx] = (bf16)t[tx][ty + i];
}

// y[n] = b[n] + sum_k W[n,k] * x[k]   (fp32; one wave per output row)
__global__ void gemv_k(const float* __restrict__ W, const float* __restrict__ x,
                       const float* __restrict__ b, float* __restrict__ y,
                       int K) {
    int n    = blockIdx.x * 4 + (threadIdx.x >> 6);
    int lane = threadIdx.x & 63;
    const float* row = W + (size_t)n * K;
    float s = 0.0f;
    for (int k = lane * 4; k < K; k += 256) {
        f32x4 w = *(const f32x4*)(row + k);
        f32x4 xv = *(const f32x4*)(x + k);
        s += w[0] * xv[0] + w[1] * xv[1] + w[2] * xv[2] + w[3] * xv[3];
    }
#pragma unroll
    for (int off = 32; off; off >>= 1) s += __shfl_down(s, off);
    if (lane == 0) y[n] = s + b[n];
}

// GRU combine, in place: upd (=gated buffer) = (1-z)*n + z*gated
__global__ void gru_combine_k(const bf16* __restrict__ gi,
                              const bf16* __restrict__ gh,
                              bf16* __restrict__ gated) {
    int i   = blockIdx.x * 256 + threadIdx.x;
    int row = i >> 7;
    int c   = (i & 127) << 3;
    size_t b3 = (size_t)row * 3072 + c;
    size_t b1 = (size_t)row * 1024 + c;
    bf16x8 gir = *(const bf16x8*)(gi + b3);
    bf16x8 giz = *(const bf16x8*)(gi + b3 + 1024);
    bf16x8 gin = *(const bf16x8*)(gi + b3 + 2048);
    bf16x8 ghr = *(const bf16x8*)(gh + b3);
    bf16x8 ghz = *(const bf16x8*)(gh + b3 + 1024);
    bf16x8 ghn = *(const bf16x8*)(gh + b3 + 2048);
    bf16x8 g   = *(const bf16x8*)(gated + b1);
    bf16x8 o;
#pragma unroll
    for (int e = 0; e < 8; ++e) {
        float r = sigmoid_f((float)gir[e] + (float)ghr[e]);
        float z = sigmoid_f((float)giz[e] + (float)ghz[e]);
        float n = tanh_f((float)gin[e] + r * (float)ghn[e]);
        o[e] = (bf16)((1.0f - z) * n + z * (float)g[e]);
    }
    *(bf16x8*)(gated + b1) = o;
}

__global__ void fill_ones_k(float* __restrict__ p, int n) {
    int i = blockIdx.x * 256 + threadIdx.x;
    if (i < n) p[i] = 1.0f;
}

// ---------------------------------------------------------------------------
// Launch
// ---------------------------------------------------------------------------
extern "C" void kernel_launch(void* const* d_in, const int* in_sizes, int n_in,
                              void* d_out, int out_size, void* d_ws,
                              size_t ws_size, hipStream_t stream) {
    const float* input      = (const float*)d_in[0];
    const float* prev       = (const float*)d_in[1];
    const float* in_proj_w  = (const float*)d_in[2];
    const float* in_proj_b  = (const float*)d_in[3];
    const float* out_proj_w = (const float*)d_in[4];
    const float* out_proj_b = (const float*)d_in[5];
    const float* ip_w       = (const float*)d_in[6];
    const float* ip_b       = (const float*)d_in[7];
    // d_in[8]/d_in[9] (mp_w/mp_b) dead: softmax over one key == 1
    const float* fg_w  = (const float*)d_in[10];
    const float* fg_b  = (const float*)d_in[11];
    const float* og_w  = (const float*)d_in[12];
    const float* og_b  = (const float*)d_in[13];
    const float* gih_w = (const float*)d_in[14];
    const float* gih_b = (const float*)d_in[15];
    const float* ghh_w = (const float*)d_in[16];
    const float* ghh_b = (const float*)d_in[17];
    float* out = (float*)d_out;

    // ---- workspace layout (152 MiB, overlaps respect dependency order)
    char* ws = (char*)d_ws;
    const size_t MB = 1024 * 1024;
    bf16* CAT   = (bf16*)(ws);             // [0,32M)  live until gi done
    bf16* WHHB  = (bf16*)(ws);             // 6M, cast AFTER gi (overlaps CAT)
    bf16* GI    = (bf16*)(ws + 32 * MB);   // [32,80M)
    bf16* GH    = (bf16*)(ws + 80 * MB);   // [80,128M) written late
    // temporaries inside the GH region (dead before GH is written):
    bf16* WVB   = (bf16*)(ws + 80 * MB);   // 2M
    bf16* WOPB  = (bf16*)(ws + 82 * MB);   // 2M
    bf16* WIHB  = (bf16*)(ws + 84 * MB);   // 6M
    bf16* WIPT  = (bf16*)(ws + 90 * MB);   // 2M
    bf16* T1T   = (bf16*)(ws + 92 * MB);   // 2M
    bf16* T2T   = (bf16*)(ws + 94 * MB);   // 2M
    bf16* WFGB  = (bf16*)(ws + 96 * MB);   // 4M
    float* T1B  = (float*)(ws + 100 * MB);
    float* T2B  = (float*)(ws + 100 * MB + 8192);
    float* T3B  = (float*)(ws + 100 * MB + 16384);
    bf16* GATED = (bf16*)(ws + 128 * MB);  // [128,144M); becomes UPD in place
    bf16* WCOMB = (bf16*)(ws + 144 * MB);  // [144,150M)
    bf16* WOGB  = (bf16*)(ws + 150 * MB);  // [150,152M)

    const int M = B_ROWS;
    dim3 blk(256);

    // 1. activations -> bf16 concat
    build_cat_k<<<dim3((M * 2048 / 4) / 256), blk, 0, stream>>>(prev, input, CAT);
    // 2. all front weight casts in one launch
    cast_weights_k<<<dim3(8192), blk, 0, stream>>>(
        in_proj_w + 2048 * 1024, out_proj_w, gih_w, fg_w, og_w,
        WVB, WOPB, WIHB, WFGB, WOGB);
    // 3. Wip^T (bf16)
    transpose_cast_k<<<dim3(32, 32), blk, 0, stream>>>(ip_w, WIPT, 1024, 1024);
    // 4. bias chain (fp32, exact)
    gemv_k<<<dim3(256), blk, 0, stream>>>(in_proj_w + 2048 * 1024, ip_b, in_proj_b + 2048, T1B, 1024);
    gemv_k<<<dim3(256), blk, 0, stream>>>(out_proj_w, T1B, out_proj_b, T2B, 1024);
    gemv_k<<<dim3(768), blk, 0, stream>>>(gih_w, T2B, gih_b, T3B, 1024);
    // 5-7. weight composition: Wcomb = Wih @ Wop @ Wv @ Wip
    gemm64_k<<<dim3(128), blk, 0, stream>>>(WVB, 1024, WIPT, 1024, nullptr,
        1024, 1024, 3, T1T, nullptr, nullptr, nullptr, 1024, 16);  // (Wv@Wip)^T
    gemm64_k<<<dim3(128), blk, 0, stream>>>(WOPB, 1024, T1T, 1024, nullptr,
        1024, 1024, 3, T2T, nullptr, nullptr, nullptr, 1024, 16);  // (Wop@..)^T
    gemm64_k<<<dim3(384), blk, 0, stream>>>(WIHB, 1024, T2T, 1024, nullptr,
        1024, 1024, 0, WCOMB, nullptr, nullptr, nullptr, 0, 48);   // Wcomb
    // 8. gated = prev * sigmoid(cat @ Wfg^T + bfg)
    gemm128_k<<<dim3(512), blk, 0, stream>>>(CAT, 2048, WFGB, 2048,
        fg_b, 1024, 2048, 1, GATED, nullptr, prev, nullptr, 0, 64);
    // 9. gi = x @ Wcomb^T + bcomb
    gemm128_k<<<dim3(1536), blk, 0, stream>>>(CAT + 1024, 2048, WCOMB,
        1024, T3B, 3072, 1024, 0, GI, nullptr, nullptr, nullptr, 0, 64);
    // 10. Whh cast (CAT now dead)
    cast_f32_bf16_k<<<dim3(3072), blk, 0, stream>>>(ghh_w, WHHB, 3072 * 1024 / 4);
    // 11. gh = gated @ Whh^T + bhh
    gemm128_k<<<dim3(1536), blk, 0, stream>>>(GATED, 1024, WHHB, 1024,
        ghh_b, 3072, 1024, 0, GH, nullptr, nullptr, nullptr, 0, 64);
    // 12. GRU combine (in place: GATED becomes UPD)
    gru_combine_k<<<dim3(M * 1024 / 8 / 256), blk, 0, stream>>>(GI, GH, GATED);
    // 13. out = upd * sigmoid(upd @ Wog^T + bog)
    gemm128_k<<<dim3(512), blk, 0, stream>>>(GATED, 1024, WOGB, 1024,
        og_b, 1024, 1024, 2, nullptr, out, nullptr, GATED, 0, 64);
    // 14. attention weights == 1.0
    fill_ones_k<<<dim3(32), blk, 0, stream>>>(out + (size_t)M * 1024, M);
}